// Round 22
// baseline (78.087 us; speedup 1.0000x reference)
//
#include <hip/hip_runtime.h>
#include <hip/hip_bf16.h>

#define LOG2E 1.4426950408889634f

typedef __attribute__((ext_vector_type(8))) short bf16x8;
typedef __attribute__((ext_vector_type(4))) float f32x4;
typedef __attribute__((ext_vector_type(16))) float f32x16;

__device__ __forceinline__ short f2bf(float a) {
  __hip_bfloat16 h = __float2bfloat16(a);
  return *reinterpret_cast<short*>(&h);
}
__device__ __forceinline__ unsigned pkbf(float a, float b) {
  return (unsigned)(unsigned short)f2bf(a) | ((unsigned)(unsigned short)f2bf(b) << 16);
}
__device__ __forceinline__ unsigned cvtpk(float a, float b) {
  unsigned r;
  asm("v_cvt_pk_bf16_f32 %0, %1, %2" : "=v"(r) : "v"(a), "v"(b));
  return r;
}
__device__ __forceinline__ float bfu2f(unsigned u16v) {
  unsigned v = u16v << 16; float f; __builtin_memcpy(&f, &v, 4); return f;
}
__device__ __forceinline__ float exthi(unsigned u) {
  unsigned v = u & 0xffff0000u; float f; __builtin_memcpy(&f, &v, 4); return f;
}
union FragU8 { unsigned d[4]; bf16x8 v; };
union KU { uint4 u; bf16x8 v; };

// ---------------- Kernel 0: transpose-convert + W convert + V-border zero ----
__global__ __launch_bounds__(256) void haloattn_cvt(
    const float* __restrict__ x, const float* __restrict__ q_w,
    const float* __restrict__ kv_w, unsigned short* __restrict__ xT,
    unsigned short* __restrict__ w_bf, unsigned short* __restrict__ vpln)
{
  __shared__ float Ld[64][68];
  const int t = threadIdx.x;
  const int pt = blockIdx.x, kt = blockIdx.y, b = blockIdx.z;
  const int flat = ((b << 2) + kt) * 64 + pt;   // 0..2047, unique per block
  {
    const int idx = flat * 64 + (t & 63);
    if (t < 64) {
      const float wv = (idx < 32768) ? q_w[idx] : kv_w[idx - 32768];
      w_bf[idx] = (unsigned short)f2bf(wv);
    }
  }
  {
    unsigned short* pl = vpln + (size_t)flat * 5040;
    for (int e = t; e < 944; e += 256) {
      int off;
      if (e < 216) {
        off = e;
      } else if (e < 432) {
        off = 4824 + (e - 216);
      } else {
        const int tt = e - 432;
        const int y = 3 + (tt >> 3);
        const int cidx = tt & 7;
        off = y * 72 + (cidx < 3 ? cidx : cidx + 64);
      }
      pl[off] = 0;
    }
  }
  const float* xb = x + ((size_t)b * 256 + (kt << 6)) * 4096 + (pt << 6);
#pragma unroll
  for (int ps = 0; ps < 4; ++ps) {
    const int kloc = (ps << 4) + (t >> 4);
    const int ploc = (t & 15) << 2;
    float4 v = *(const float4*)(xb + (size_t)kloc * 4096 + ploc);
    *(float4*)&Ld[kloc][ploc] = v;
  }
  __syncthreads();
  const int pl = t >> 2;
  const int ks = (t & 3) << 4;
  float f[16];
#pragma unroll
  for (int i = 0; i < 16; ++i) f[i] = Ld[ks + i][pl];
  uint4 o0, o1;
  o0.x = pkbf(f[0], f[1]);   o0.y = pkbf(f[2], f[3]);
  o0.z = pkbf(f[4], f[5]);   o0.w = pkbf(f[6], f[7]);
  o1.x = pkbf(f[8], f[9]);   o1.y = pkbf(f[10], f[11]);
  o1.z = pkbf(f[12], f[13]); o1.w = pkbf(f[14], f[15]);
  unsigned short* op = xT + ((size_t)(b << 12) + (pt << 6) + pl) * 256 + (kt << 6) + ks;
  *(uint4*)op = o0;
  *(uint4*)(op + 8) = o1;
}

// ---------------- Kernel 1: fused q/kv projection (bf16 MFMA) ----------------
__global__ __launch_bounds__(512, 4) void haloattn_proj_mfma(
    const unsigned short* __restrict__ xT, const unsigned short* __restrict__ w_bf,
    unsigned short* __restrict__ q_bf, unsigned short* __restrict__ kbuf,
    unsigned short* __restrict__ vpln)
{
  __shared__ unsigned short Wt[256][68];
  __shared__ unsigned short Xt[128][68];
  const int tid = threadIdx.x;
  const int w = tid >> 6, l = tid & 63;
  const int b = blockIdx.z, oBase = blockIdx.y << 8, pBase = blockIdx.x << 7;
  const int wm = w >> 1, wn = w & 1;
  const int g = l >> 4, c = l & 15;

  f32x4 acc[4][4] = {};

  const int srow = tid >> 3;
  const int se3  = (tid & 7) << 3;

  for (int chk = 0; chk < 4; ++chk) {
    const int k0 = chk << 6;
#pragma unroll
    for (int ps = 0; ps < 4; ++ps) {
      const int row = (ps << 6) + srow;
      uint4 wv = *(const uint4*)(w_bf + (size_t)(oBase + row) * 256 + k0 + se3);
      char* dst = (char*)&Wt[0][0] + row * 136 + (se3 << 1);
      *(uint2*)dst = make_uint2(wv.x, wv.y);
      *(uint2*)(dst + 8) = make_uint2(wv.z, wv.w);
    }
#pragma unroll
    for (int ps = 0; ps < 2; ++ps) {
      const int p = (ps << 6) + srow;
      uint4 xv = *(const uint4*)(xT + ((size_t)(b << 12) + pBase + p) * 256 + k0 + se3);
      char* dst = (char*)&Xt[0][0] + p * 136 + (se3 << 1);
      *(uint2*)dst = make_uint2(xv.x, xv.y);
      *(uint2*)(dst + 8) = make_uint2(xv.z, xv.w);
    }
    __syncthreads();
#pragma unroll
    for (int kk = 0; kk < 2; ++kk) {
      FragU8 bfr[4];
#pragma unroll
      for (int nf = 0; nf < 4; ++nf) {
        const char* src = (const char*)&Xt[0][0]
            + ((wn << 6) + (nf << 4) + c) * 136 + (kk << 6) + (g << 4);
        uint2 lo = *(const uint2*)src, hi2 = *(const uint2*)(src + 8);
        bfr[nf].d[0] = lo.x; bfr[nf].d[1] = lo.y;
        bfr[nf].d[2] = hi2.x; bfr[nf].d[3] = hi2.y;
      }
#pragma unroll
      for (int mf = 0; mf < 4; ++mf) {
        const char* src = (const char*)&Wt[0][0]
            + ((wm << 6) + (mf << 4) + c) * 136 + (kk << 6) + (g << 4);
        uint2 lo = *(const uint2*)src, hi2 = *(const uint2*)(src + 8);
        FragU8 af;
        af.d[0] = lo.x; af.d[1] = lo.y; af.d[2] = hi2.x; af.d[3] = hi2.y;
#pragma unroll
        for (int nf = 0; nf < 4; ++nf)
          acc[mf][nf] = __builtin_amdgcn_mfma_f32_16x16x32_bf16(af.v, bfr[nf].v, acc[mf][nf], 0, 0, 0);
      }
    }
    __syncthreads();
  }
#pragma unroll
  for (int mf = 0; mf < 4; ++mf) {
    const int o = oBase + (wm << 6) + (mf << 4) + (g << 2);
#pragma unroll
    for (int nf = 0; nf < 4; ++nf) {
      const int p = pBase + (wn << 6) + (nf << 4) + c;
      if (o < 128) {
        uint2 pk2 = make_uint2(pkbf(acc[mf][nf][0], acc[mf][nf][1]),
                               pkbf(acc[mf][nf][2], acc[mf][nf][3]));
        const int head = o >> 4;
        const int z = (b << 3) + head;
        const int y = p >> 6, xx = p & 63;
        const int nbb = ((y >> 3) << 3) + (xx >> 3);
        const int qi = ((y & 7) << 3) + (xx & 7);
        *(uint2*)(q_bf + (((size_t)z * 64 + nbb) * 64 + qi) * 16 + (o & 15)) = pk2;
      } else {
        const int ch = o - 128;
        const int head = (ch * 1366) >> 16;      // ch/48
        const int wi = ch - head * 48;
        const int b8h = (b << 3) + head;
        if (wi < 16) {
          uint2 pk2 = make_uint2(pkbf(acc[mf][nf][0], acc[mf][nf][1]),
                                 pkbf(acc[mf][nf][2], acc[mf][nf][3]));
          *(uint2*)(kbuf + ((size_t)b8h * 4096 + p) * 16 + wi) = pk2;
        } else {
          const int d = wi - 16;
          const int y = p >> 6, xx = p & 63;
          unsigned short* vp = vpln + (size_t)(b8h * 32 + d) * 5040
                               + (size_t)(y + 3) * 72 + (xx + 3);
          vp[0]     = (unsigned short)f2bf(acc[mf][nf][0]);
          vp[5040]  = (unsigned short)f2bf(acc[mf][nf][1]);
          vp[10080] = (unsigned short)f2bf(acc[mf][nf][2]);
          vp[15120] = (unsigned short)f2bf(acc[mf][nf][3]);
        }
      }
    }
  }
}

// ---- attn per-chunk body: H bias from packed register, repack via permlane ----
__device__ __forceinline__ void attn_chunk(
    unsigned hpkc, const bf16x8 kf, const bf16x8 vf0, const bf16x8 vf1,
    const float* __restrict__ wreg,
    const bf16x8 qfrag, f32x16& acc, float& lrow, int hi, float qs)
{
  const f32x16 z16 = {};
  __builtin_amdgcn_s_setprio(1);
  f32x16 Cs = __builtin_amdgcn_mfma_f32_32x32x16_bf16(kf, qfrag, z16, 0, 0, 0);
  __builtin_amdgcn_s_setprio(0);
  const float hA = bfu2f(hpkc & 0xffffu);
  const float hB = exthi(hpkc);
  float p[16];
#pragma unroll
  for (int r = 0; r < 16; ++r) {
    const float wv = wreg[(r & 3) + 4 * ((r >> 2) & 1)];
    const float h = (r < 8) ? hA : hB;
    p[r] = exp2f(fmaf(Cs[r], qs, h + wv));
  }
  {
    float s0 = (p[0] + p[1]) + (p[2] + p[3]);
    float s1 = (p[4] + p[5]) + (p[6] + p[7]);
    float s2 = (p[8] + p[9]) + (p[10] + p[11]);
    float s3 = (p[12] + p[13]) + (p[14] + p[15]);
    lrow += (s0 + s1) + (s2 + s3);
  }
  unsigned dw[8];
#pragma unroll
  for (int k = 0; k < 8; ++k) dw[k] = cvtpk(p[2 * k], p[2 * k + 1]);
  unsigned a0 = dw[0], b0 = dw[2];
  unsigned a1 = dw[1], b1 = dw[3];
  unsigned a2 = dw[4], b2 = dw[6];
  unsigned a3 = dw[5], b3 = dw[7];
  asm("v_permlane32_swap_b32 %0, %1" : "+v"(a0), "+v"(b0));
  asm("v_permlane32_swap_b32 %0, %1" : "+v"(a1), "+v"(b1));
  asm("v_permlane32_swap_b32 %0, %1" : "+v"(a2), "+v"(b2));
  asm("v_permlane32_swap_b32 %0, %1" : "+v"(a3), "+v"(b3));
  FragU8 f0, f1;
  f0.d[0] = a0; f0.d[1] = a1; f0.d[2] = b0; f0.d[3] = b1;
  f1.d[0] = a2; f1.d[1] = a3; f1.d[2] = b2; f1.d[3] = b3;
  __builtin_amdgcn_s_setprio(1);
  acc = __builtin_amdgcn_mfma_f32_32x32x16_bf16(vf0, f0.v, acc, 0, 0, 0);
  acc = __builtin_amdgcn_mfma_f32_32x32x16_bf16(vf1, f1.v, acc, 0, 0, 0);
  __builtin_amdgcn_s_setprio(0);
}

// ---------------- Kernel 2: halo attention, q-half waves, reg-resident biases ----
// launch_bounds (128,4): cap VGPR at 128 -> 4 waves/SIMD occupancy step (m69).
// Post-r18 per-wave state (~110-125 regs) should fit; r10's spill was the old
// full-state design. Falsifiable: spill shows as WRITE_SIZE >> 33.5 MB.
__global__ __launch_bounds__(128, 4) void haloattn_attn_direct(
    const unsigned short* __restrict__ q_bf, const unsigned short* __restrict__ kbuf,
    const unsigned short* __restrict__ vpln,
    const float* __restrict__ height_rel, const float* __restrict__ width_rel,
    float* __restrict__ out)
{
  __shared__ __align__(16) unsigned short SM[5376];

  const int tid = threadIdx.x;
  const int w = tid >> 6;          // wave id = nt half
  const int l = tid & 63;
  const int q32 = l & 31, hi = l >> 5;
  const int wg = blockIdx.x;
  const int swz = ((wg & 7) << 9) | (wg >> 3);
  const int z = swz >> 6;
  const int nb = swz & 63;
  const int b = z >> 3, head = z & 7;
  const int bi = nb >> 3, bj = nb & 7;
  const f32x16 z16 = {};
  const float qs = 0.25f * LOG2E;

  const unsigned short* qtile = q_bf + ((size_t)z * 64 + nb) * 1024;
  const bf16x8 qfrag = *(const bf16x8*)(qtile + (((w << 5) + q32) << 4) + 8 * hi);

  unsigned short* HRs = SM;
  unsigned short* WRs = SM + 768;
  if (tid < 54) {
    const int u = tid >> 1, d0 = (tid & 1) << 3;
    float4 a = *(const float4*)(height_rel + u * 16 + d0);
    float4 b4 = *(const float4*)(height_rel + u * 16 + d0 + 4);
    uint4 o;
    o.x = cvtpk(a.x * LOG2E, a.y * LOG2E);
    o.y = cvtpk(a.z * LOG2E, a.w * LOG2E);
    o.z = cvtpk(b4.x * LOG2E, b4.y * LOG2E);
    o.w = cvtpk(b4.z * LOG2E, b4.w * LOG2E);
    *(uint4*)(HRs + u * 24 + d0) = o;
    a = *(const float4*)(width_rel + u * 16 + d0);
    b4 = *(const float4*)(width_rel + u * 16 + d0 + 4);
    o.x = cvtpk(a.x * LOG2E, a.y * LOG2E);
    o.y = cvtpk(a.z * LOG2E, a.w * LOG2E);
    o.z = cvtpk(b4.x * LOG2E, b4.y * LOG2E);
    o.w = cvtpk(b4.z * LOG2E, b4.w * LOG2E);
    *(uint4*)(WRs + u * 24 + d0) = o;
  } else if (tid < 64) {
    const int t = tid - 54;
    const int u = 27 + (t >> 1), d0 = (t & 1) << 3;
    uint4 o = {};
    *(uint4*)(HRs + u * 24 + d0) = o;
    *(uint4*)(WRs + u * 24 + d0) = o;
  }
  __syncthreads();

  {
    bf16x8 hfr = *(const bf16x8*)((const char*)HRs + q32 * 48 + 16 * hi);
    bf16x8 wfr = *(const bf16x8*)((const char*)WRs + q32 * 48 + 16 * hi);
    f32x16 hC = __builtin_amdgcn_mfma_f32_32x32x16_bf16(hfr, qfrag, z16, 0, 0, 0);
    f32x16 wC = __builtin_amdgcn_mfma_f32_32x32x16_bf16(wfr, qfrag, z16, 0, 0, 0);
    __syncthreads();
#pragma unroll
    for (int r = 0; r < 16; ++r) {
      const int u = (r & 3) + 8 * (r >> 2) + 4 * hi;
      if (u >= 6 && u < 27) {
        const int rr = (w * 21) + (u - 6);
        SM[rr * 64 + q32]        = (unsigned short)f2bf(hC[r]);
        SM[2688 + rr * 64 + q32] = (unsigned short)f2bf(wC[r]);
      }
    }
  }
  __syncthreads();

  const int qw = q32 & 7;
  float wreg[8];
#pragma unroll
  for (int t = 0; t < 8; ++t) {
    const int jt = (t < 4 ? t : t + 4) + 4 * hi;
    if (jt < 14)
      wreg[t] = bfu2f(SM[2688 + (w * 21 + 7 - qw + jt) * 64 + q32]);
    else
      wreg[t] = -1e30f;
  }

  // ---- H bias hoist: 14 LDS reads -> 7 packed regs ----
  const int qh0 = q32 >> 3;
  const unsigned short* Hp = SM + ((w ? 24 : 7) - qh0) * 64 + q32;
  unsigned hpk[7];
#pragma unroll
  for (int c7 = 0; c7 < 7; ++c7) {
    const unsigned lo = Hp[(2 * c7) * 64];
    const unsigned hi2 = Hp[(2 * c7 + 1) * 64];
    hpk[c7] = lo | (hi2 << 16);
  }

  const int jj = q32 & 15, ir = q32 >> 4;
  const int xx = bj * 8 + jj - 3;
  const bool jok = (jj < 14) && ((unsigned)xx < 64u);
  const unsigned short* kb = kbuf + ((size_t)((b << 3) + head) * 4096 + xx) * 16 + 8 * hi;
  const int yy0 = bi * 8 + ir - 3;
  const unsigned short* vb = vpln + (size_t)(((b << 3) + head) * 32 + q32) * 5040
                             + (bi * 8) * 72 + bj * 8 + 8 * hi;

  f32x16 acc = {};
  float lrow = 0.f;

#define LK(cc, dst) { dst.u = make_uint4(0,0,0,0); const int yy = yy0 + 2*(cc); \
    if (jok && (unsigned)yy < 64u) dst.u = *(const uint4*)(kb + (size_t)yy * 1024); }
#define LV(cc, d0, d1) { d0 = *(const bf16x8*)(vb + (2*(cc)) * 72); \
    d1 = *(const bf16x8*)(vb + (2*(cc)+1) * 72); }

  KU kA, kB;
  bf16x8 vA0, vA1, vB0, vB1;
  LK(0, kA); LV(0, vA0, vA1);
  LK(1, kB); LV(1, vB0, vB1);

  { KU kn; bf16x8 n0, n1; LK(2, kn); LV(2, n0, n1);
    attn_chunk(hpk[0], kA.v, vA0, vA1, wreg, qfrag, acc, lrow, hi, qs);
    kA = kn; vA0 = n0; vA1 = n1; }
  { KU kn; bf16x8 n0, n1; LK(3, kn); LV(3, n0, n1);
    attn_chunk(hpk[1], kB.v, vB0, vB1, wreg, qfrag, acc, lrow, hi, qs);
    kB = kn; vB0 = n0; vB1 = n1; }
  { KU kn; bf16x8 n0, n1; LK(4, kn); LV(4, n0, n1);
    attn_chunk(hpk[2], kA.v, vA0, vA1, wreg, qfrag, acc, lrow, hi, qs);
    kA = kn; vA0 = n0; vA1 = n1; }
  { KU kn; bf16x8 n0, n1; LK(5, kn); LV(5, n0, n1);
    attn_chunk(hpk[3], kB.v, vB0, vB1, wreg, qfrag, acc, lrow, hi, qs);
    kB = kn; vB0 = n0; vB1 = n1; }
  { KU kn; bf16x8 n0, n1; LK(6, kn); LV(6, n0, n1);
    attn_chunk(hpk[4], kA.v, vA0, vA1, wreg, qfrag, acc, lrow, hi, qs);
    kA = kn; vA0 = n0; vA1 = n1; }
  attn_chunk(hpk[5], kB.v, vB0, vB1, wreg, qfrag, acc, lrow, hi, qs);
  attn_chunk(hpk[6], kA.v, vA0, vA1, wreg, qfrag, acc, lrow, hi, qs);

#undef LK
#undef LV

  const float L = lrow + __shfl_xor(lrow, 32);
  const float invL = 1.f / L;
  const int qt = (w << 5) + q32;
  const int yq = bi * 8 + (qt >> 3);
  const int xq = bj * 8 + (q32 & 7);
  float* obase = out + ((size_t)(b * 256 + head * 32) * 4096) + yq * 64 + xq;
#pragma unroll
  for (int r = 0; r < 16; ++r) {
    const int d = (r & 3) + 8 * (r >> 2) + 4 * hi;
    obase[(size_t)d * 4096] = acc[r] * invL;
  }
}

extern "C" void kernel_launch(void* const* d_in, const int* in_sizes, int n_in,
                              void* d_out, int out_size, void* d_ws, size_t ws_size,
                              hipStream_t stream) {
  const float* x          = (const float*)d_in[0];
  const float* q_w        = (const float*)d_in[1];
  const float* kv_w       = (const float*)d_in[2];
  const float* height_rel = (const float*)d_in[3];
  const float* width_rel  = (const float*)d_in[4];
  float* out = (float*)d_out;

  unsigned short* q_bf = (unsigned short*)d_ws;            // 4,194,304 u16
  unsigned short* xT   = q_bf + (size_t)4194304;           // 8,388,608 u16
  unsigned short* w_bf = xT + (size_t)8388608;             //   131,072 u16
  unsigned short* kbuf = w_bf + (size_t)131072;            // 4,194,304 u16
  unsigned short* vpln = kbuf + (size_t)4194304;           // 10,321,920 u16

  haloattn_cvt<<<dim3(64, 4, 8), 256, 0, stream>>>(x, q_w, kv_w, xT, w_bf, vpln);
  haloattn_proj_mfma<<<dim3(32, 2, 8), 512, 0, stream>>>(xT, w_bf, q_bf, kbuf, vpln);
  haloattn_attn_direct<<<4096, 128, 0, stream>>>(q_bf, kbuf, vpln,
                                                 height_rel, width_rel, out);
}

// Round 23
// 64.834 us; speedup vs baseline: 1.2044x; 1.2044x over previous
//
#include <hip/hip_runtime.h>
#include <hip/hip_bf16.h>

#define LOG2E 1.4426950408889634f

typedef __attribute__((ext_vector_type(8))) short bf16x8;
typedef __attribute__((ext_vector_type(4))) float f32x4;
typedef __attribute__((ext_vector_type(16))) float f32x16;

__device__ __forceinline__ short f2bf(float a) {
  __hip_bfloat16 h = __float2bfloat16(a);
  return *reinterpret_cast<short*>(&h);
}
__device__ __forceinline__ unsigned pkbf(float a, float b) {
  return (unsigned)(unsigned short)f2bf(a) | ((unsigned)(unsigned short)f2bf(b) << 16);
}
__device__ __forceinline__ unsigned cvtpk(float a, float b) {
  unsigned r;
  asm("v_cvt_pk_bf16_f32 %0, %1, %2" : "=v"(r) : "v"(a), "v"(b));
  return r;
}
__device__ __forceinline__ float bfu2f(unsigned u16v) {
  unsigned v = u16v << 16; float f; __builtin_memcpy(&f, &v, 4); return f;
}
__device__ __forceinline__ float exthi(unsigned u) {
  unsigned v = u & 0xffff0000u; float f; __builtin_memcpy(&f, &v, 4); return f;
}
union FragU8 { unsigned d[4]; bf16x8 v; };
union KU { uint4 u; bf16x8 v; };

// ---------------- Kernel 0: transpose-convert + W convert + V-border zero ----
__global__ __launch_bounds__(256) void haloattn_cvt(
    const float* __restrict__ x, const float* __restrict__ q_w,
    const float* __restrict__ kv_w, unsigned short* __restrict__ xT,
    unsigned short* __restrict__ w_bf, unsigned short* __restrict__ vpln)
{
  __shared__ float Ld[64][68];
  const int t = threadIdx.x;
  const int pt = blockIdx.x, kt = blockIdx.y, b = blockIdx.z;
  const int flat = ((b << 2) + kt) * 64 + pt;   // 0..2047, unique per block
  {
    const int idx = flat * 64 + (t & 63);
    if (t < 64) {
      const float wv = (idx < 32768) ? q_w[idx] : kv_w[idx - 32768];
      w_bf[idx] = (unsigned short)f2bf(wv);
    }
  }
  {
    unsigned short* pl = vpln + (size_t)flat * 5040;
    for (int e = t; e < 944; e += 256) {
      int off;
      if (e < 216) {
        off = e;
      } else if (e < 432) {
        off = 4824 + (e - 216);
      } else {
        const int tt = e - 432;
        const int y = 3 + (tt >> 3);
        const int cidx = tt & 7;
        off = y * 72 + (cidx < 3 ? cidx : cidx + 64);
      }
      pl[off] = 0;
    }
  }
  const float* xb = x + ((size_t)b * 256 + (kt << 6)) * 4096 + (pt << 6);
#pragma unroll
  for (int ps = 0; ps < 4; ++ps) {
    const int kloc = (ps << 4) + (t >> 4);
    const int ploc = (t & 15) << 2;
    float4 v = *(const float4*)(xb + (size_t)kloc * 4096 + ploc);
    *(float4*)&Ld[kloc][ploc] = v;
  }
  __syncthreads();
  const int pl = t >> 2;
  const int ks = (t & 3) << 4;
  float f[16];
#pragma unroll
  for (int i = 0; i < 16; ++i) f[i] = Ld[ks + i][pl];
  uint4 o0, o1;
  o0.x = pkbf(f[0], f[1]);   o0.y = pkbf(f[2], f[3]);
  o0.z = pkbf(f[4], f[5]);   o0.w = pkbf(f[6], f[7]);
  o1.x = pkbf(f[8], f[9]);   o1.y = pkbf(f[10], f[11]);
  o1.z = pkbf(f[12], f[13]); o1.w = pkbf(f[14], f[15]);
  unsigned short* op = xT + ((size_t)(b << 12) + (pt << 6) + pl) * 256 + (kt << 6) + ks;
  *(uint4*)op = o0;
  *(uint4*)(op + 8) = o1;
}

// ---------------- Kernel 1: fused q/kv projection (bf16 MFMA) ----------------
__global__ __launch_bounds__(512, 4) void haloattn_proj_mfma(
    const unsigned short* __restrict__ xT, const unsigned short* __restrict__ w_bf,
    unsigned short* __restrict__ q_bf, unsigned short* __restrict__ kbuf,
    unsigned short* __restrict__ vpln)
{
  __shared__ unsigned short Wt[256][68];
  __shared__ unsigned short Xt[128][68];
  const int tid = threadIdx.x;
  const int w = tid >> 6, l = tid & 63;
  const int b = blockIdx.z, oBase = blockIdx.y << 8, pBase = blockIdx.x << 7;
  const int wm = w >> 1, wn = w & 1;
  const int g = l >> 4, c = l & 15;

  f32x4 acc[4][4] = {};

  const int srow = tid >> 3;
  const int se3  = (tid & 7) << 3;

  for (int chk = 0; chk < 4; ++chk) {
    const int k0 = chk << 6;
#pragma unroll
    for (int ps = 0; ps < 4; ++ps) {
      const int row = (ps << 6) + srow;
      uint4 wv = *(const uint4*)(w_bf + (size_t)(oBase + row) * 256 + k0 + se3);
      char* dst = (char*)&Wt[0][0] + row * 136 + (se3 << 1);
      *(uint2*)dst = make_uint2(wv.x, wv.y);
      *(uint2*)(dst + 8) = make_uint2(wv.z, wv.w);
    }
#pragma unroll
    for (int ps = 0; ps < 2; ++ps) {
      const int p = (ps << 6) + srow;
      uint4 xv = *(const uint4*)(xT + ((size_t)(b << 12) + pBase + p) * 256 + k0 + se3);
      char* dst = (char*)&Xt[0][0] + p * 136 + (se3 << 1);
      *(uint2*)dst = make_uint2(xv.x, xv.y);
      *(uint2*)(dst + 8) = make_uint2(xv.z, xv.w);
    }
    __syncthreads();
#pragma unroll
    for (int kk = 0; kk < 2; ++kk) {
      FragU8 bfr[4];
#pragma unroll
      for (int nf = 0; nf < 4; ++nf) {
        const char* src = (const char*)&Xt[0][0]
            + ((wn << 6) + (nf << 4) + c) * 136 + (kk << 6) + (g << 4);
        uint2 lo = *(const uint2*)src, hi2 = *(const uint2*)(src + 8);
        bfr[nf].d[0] = lo.x; bfr[nf].d[1] = lo.y;
        bfr[nf].d[2] = hi2.x; bfr[nf].d[3] = hi2.y;
      }
#pragma unroll
      for (int mf = 0; mf < 4; ++mf) {
        const char* src = (const char*)&Wt[0][0]
            + ((wm << 6) + (mf << 4) + c) * 136 + (kk << 6) + (g << 4);
        uint2 lo = *(const uint2*)src, hi2 = *(const uint2*)(src + 8);
        FragU8 af;
        af.d[0] = lo.x; af.d[1] = lo.y; af.d[2] = hi2.x; af.d[3] = hi2.y;
#pragma unroll
        for (int nf = 0; nf < 4; ++nf)
          acc[mf][nf] = __builtin_amdgcn_mfma_f32_16x16x32_bf16(af.v, bfr[nf].v, acc[mf][nf], 0, 0, 0);
      }
    }
    __syncthreads();
  }
#pragma unroll
  for (int mf = 0; mf < 4; ++mf) {
    const int o = oBase + (wm << 6) + (mf << 4) + (g << 2);
#pragma unroll
    for (int nf = 0; nf < 4; ++nf) {
      const int p = pBase + (wn << 6) + (nf << 4) + c;
      if (o < 128) {
        uint2 pk2 = make_uint2(pkbf(acc[mf][nf][0], acc[mf][nf][1]),
                               pkbf(acc[mf][nf][2], acc[mf][nf][3]));
        const int head = o >> 4;
        const int z = (b << 3) + head;
        const int y = p >> 6, xx = p & 63;
        const int nbb = ((y >> 3) << 3) + (xx >> 3);
        const int qi = ((y & 7) << 3) + (xx & 7);
        *(uint2*)(q_bf + (((size_t)z * 64 + nbb) * 64 + qi) * 16 + (o & 15)) = pk2;
      } else {
        const int ch = o - 128;
        const int head = (ch * 1366) >> 16;      // ch/48
        const int wi = ch - head * 48;
        const int b8h = (b << 3) + head;
        if (wi < 16) {
          uint2 pk2 = make_uint2(pkbf(acc[mf][nf][0], acc[mf][nf][1]),
                                 pkbf(acc[mf][nf][2], acc[mf][nf][3]));
          *(uint2*)(kbuf + ((size_t)b8h * 4096 + p) * 16 + wi) = pk2;
        } else {
          const int d = wi - 16;
          const int y = p >> 6, xx = p & 63;
          unsigned short* vp = vpln + (size_t)(b8h * 32 + d) * 5040
                               + (size_t)(y + 3) * 72 + (xx + 3);
          vp[0]     = (unsigned short)f2bf(acc[mf][nf][0]);
          vp[5040]  = (unsigned short)f2bf(acc[mf][nf][1]);
          vp[10080] = (unsigned short)f2bf(acc[mf][nf][2]);
          vp[15120] = (unsigned short)f2bf(acc[mf][nf][3]);
        }
      }
    }
  }
}

// ---- attn per-chunk body: H bias from packed register, repack via permlane ----
__device__ __forceinline__ void attn_chunk(
    unsigned hpkc, const bf16x8 kf, const bf16x8 vf0, const bf16x8 vf1,
    const float* __restrict__ wreg,
    const bf16x8 qfrag, f32x16& acc, float& lrow, int hi, float qs)
{
  const f32x16 z16 = {};
  __builtin_amdgcn_s_setprio(1);
  f32x16 Cs = __builtin_amdgcn_mfma_f32_32x32x16_bf16(kf, qfrag, z16, 0, 0, 0);
  __builtin_amdgcn_s_setprio(0);
  const float hA = bfu2f(hpkc & 0xffffu);
  const float hB = exthi(hpkc);
  float p[16];
#pragma unroll
  for (int r = 0; r < 16; ++r) {
    const float wv = wreg[(r & 3) + 4 * ((r >> 2) & 1)];
    const float h = (r < 8) ? hA : hB;
    p[r] = exp2f(fmaf(Cs[r], qs, h + wv));
  }
  {
    float s0 = (p[0] + p[1]) + (p[2] + p[3]);
    float s1 = (p[4] + p[5]) + (p[6] + p[7]);
    float s2 = (p[8] + p[9]) + (p[10] + p[11]);
    float s3 = (p[12] + p[13]) + (p[14] + p[15]);
    lrow += (s0 + s1) + (s2 + s3);
  }
  unsigned dw[8];
#pragma unroll
  for (int k = 0; k < 8; ++k) dw[k] = cvtpk(p[2 * k], p[2 * k + 1]);
  unsigned a0 = dw[0], b0 = dw[2];
  unsigned a1 = dw[1], b1 = dw[3];
  unsigned a2 = dw[4], b2 = dw[6];
  unsigned a3 = dw[5], b3 = dw[7];
  asm("v_permlane32_swap_b32 %0, %1" : "+v"(a0), "+v"(b0));
  asm("v_permlane32_swap_b32 %0, %1" : "+v"(a1), "+v"(b1));
  asm("v_permlane32_swap_b32 %0, %1" : "+v"(a2), "+v"(b2));
  asm("v_permlane32_swap_b32 %0, %1" : "+v"(a3), "+v"(b3));
  FragU8 f0, f1;
  f0.d[0] = a0; f0.d[1] = a1; f0.d[2] = b0; f0.d[3] = b1;
  f1.d[0] = a2; f1.d[1] = a3; f1.d[2] = b2; f1.d[3] = b3;
  __builtin_amdgcn_s_setprio(1);
  acc = __builtin_amdgcn_mfma_f32_32x32x16_bf16(vf0, f0.v, acc, 0, 0, 0);
  acc = __builtin_amdgcn_mfma_f32_32x32x16_bf16(vf1, f1.v, acc, 0, 0, 0);
  __builtin_amdgcn_s_setprio(0);
}

// ---------------- Kernel 2: halo attention, q-half waves, reg-resident biases ----
// launch_bounds (128,2): 256-VGPR cap. (128,4) falsified in r22 — live state
// >128 VGPRs, spills (+50 MB writes, attn 25->47us). This is the best-known config.
__global__ __launch_bounds__(128, 2) void haloattn_attn_direct(
    const unsigned short* __restrict__ q_bf, const unsigned short* __restrict__ kbuf,
    const unsigned short* __restrict__ vpln,
    const float* __restrict__ height_rel, const float* __restrict__ width_rel,
    float* __restrict__ out)
{
  __shared__ __align__(16) unsigned short SM[5376];

  const int tid = threadIdx.x;
  const int w = tid >> 6;          // wave id = nt half
  const int l = tid & 63;
  const int q32 = l & 31, hi = l >> 5;
  const int wg = blockIdx.x;
  const int swz = ((wg & 7) << 9) | (wg >> 3);
  const int z = swz >> 6;
  const int nb = swz & 63;
  const int b = z >> 3, head = z & 7;
  const int bi = nb >> 3, bj = nb & 7;
  const f32x16 z16 = {};
  const float qs = 0.25f * LOG2E;

  const unsigned short* qtile = q_bf + ((size_t)z * 64 + nb) * 1024;
  const bf16x8 qfrag = *(const bf16x8*)(qtile + (((w << 5) + q32) << 4) + 8 * hi);

  unsigned short* HRs = SM;
  unsigned short* WRs = SM + 768;
  if (tid < 54) {
    const int u = tid >> 1, d0 = (tid & 1) << 3;
    float4 a = *(const float4*)(height_rel + u * 16 + d0);
    float4 b4 = *(const float4*)(height_rel + u * 16 + d0 + 4);
    uint4 o;
    o.x = cvtpk(a.x * LOG2E, a.y * LOG2E);
    o.y = cvtpk(a.z * LOG2E, a.w * LOG2E);
    o.z = cvtpk(b4.x * LOG2E, b4.y * LOG2E);
    o.w = cvtpk(b4.z * LOG2E, b4.w * LOG2E);
    *(uint4*)(HRs + u * 24 + d0) = o;
    a = *(const float4*)(width_rel + u * 16 + d0);
    b4 = *(const float4*)(width_rel + u * 16 + d0 + 4);
    o.x = cvtpk(a.x * LOG2E, a.y * LOG2E);
    o.y = cvtpk(a.z * LOG2E, a.w * LOG2E);
    o.z = cvtpk(b4.x * LOG2E, b4.y * LOG2E);
    o.w = cvtpk(b4.z * LOG2E, b4.w * LOG2E);
    *(uint4*)(WRs + u * 24 + d0) = o;
  } else if (tid < 64) {
    const int t = tid - 54;
    const int u = 27 + (t >> 1), d0 = (t & 1) << 3;
    uint4 o = {};
    *(uint4*)(HRs + u * 24 + d0) = o;
    *(uint4*)(WRs + u * 24 + d0) = o;
  }
  __syncthreads();

  {
    bf16x8 hfr = *(const bf16x8*)((const char*)HRs + q32 * 48 + 16 * hi);
    bf16x8 wfr = *(const bf16x8*)((const char*)WRs + q32 * 48 + 16 * hi);
    f32x16 hC = __builtin_amdgcn_mfma_f32_32x32x16_bf16(hfr, qfrag, z16, 0, 0, 0);
    f32x16 wC = __builtin_amdgcn_mfma_f32_32x32x16_bf16(wfr, qfrag, z16, 0, 0, 0);
    __syncthreads();
#pragma unroll
    for (int r = 0; r < 16; ++r) {
      const int u = (r & 3) + 8 * (r >> 2) + 4 * hi;
      if (u >= 6 && u < 27) {
        const int rr = (w * 21) + (u - 6);
        SM[rr * 64 + q32]        = (unsigned short)f2bf(hC[r]);
        SM[2688 + rr * 64 + q32] = (unsigned short)f2bf(wC[r]);
      }
    }
  }
  __syncthreads();

  const int qw = q32 & 7;
  float wreg[8];
#pragma unroll
  for (int t = 0; t < 8; ++t) {
    const int jt = (t < 4 ? t : t + 4) + 4 * hi;
    if (jt < 14)
      wreg[t] = bfu2f(SM[2688 + (w * 21 + 7 - qw + jt) * 64 + q32]);
    else
      wreg[t] = -1e30f;
  }

  // ---- H bias hoist: 14 LDS reads -> 7 packed regs ----
  const int qh0 = q32 >> 3;
  const unsigned short* Hp = SM + ((w ? 24 : 7) - qh0) * 64 + q32;
  unsigned hpk[7];
#pragma unroll
  for (int c7 = 0; c7 < 7; ++c7) {
    const unsigned lo = Hp[(2 * c7) * 64];
    const unsigned hi2 = Hp[(2 * c7 + 1) * 64];
    hpk[c7] = lo | (hi2 << 16);
  }

  const int jj = q32 & 15, ir = q32 >> 4;
  const int xx = bj * 8 + jj - 3;
  const bool jok = (jj < 14) && ((unsigned)xx < 64u);
  const unsigned short* kb = kbuf + ((size_t)((b << 3) + head) * 4096 + xx) * 16 + 8 * hi;
  const int yy0 = bi * 8 + ir - 3;
  const unsigned short* vb = vpln + (size_t)(((b << 3) + head) * 32 + q32) * 5040
                             + (bi * 8) * 72 + bj * 8 + 8 * hi;

  f32x16 acc = {};
  float lrow = 0.f;

#define LK(cc, dst) { dst.u = make_uint4(0,0,0,0); const int yy = yy0 + 2*(cc); \
    if (jok && (unsigned)yy < 64u) dst.u = *(const uint4*)(kb + (size_t)yy * 1024); }
#define LV(cc, d0, d1) { d0 = *(const bf16x8*)(vb + (2*(cc)) * 72); \
    d1 = *(const bf16x8*)(vb + (2*(cc)+1) * 72); }

  KU kA, kB;
  bf16x8 vA0, vA1, vB0, vB1;
  LK(0, kA); LV(0, vA0, vA1);
  LK(1, kB); LV(1, vB0, vB1);

  { KU kn; bf16x8 n0, n1; LK(2, kn); LV(2, n0, n1);
    attn_chunk(hpk[0], kA.v, vA0, vA1, wreg, qfrag, acc, lrow, hi, qs);
    kA = kn; vA0 = n0; vA1 = n1; }
  { KU kn; bf16x8 n0, n1; LK(3, kn); LV(3, n0, n1);
    attn_chunk(hpk[1], kB.v, vB0, vB1, wreg, qfrag, acc, lrow, hi, qs);
    kB = kn; vB0 = n0; vB1 = n1; }
  { KU kn; bf16x8 n0, n1; LK(4, kn); LV(4, n0, n1);
    attn_chunk(hpk[2], kA.v, vA0, vA1, wreg, qfrag, acc, lrow, hi, qs);
    kA = kn; vA0 = n0; vA1 = n1; }
  { KU kn; bf16x8 n0, n1; LK(5, kn); LV(5, n0, n1);
    attn_chunk(hpk[3], kB.v, vB0, vB1, wreg, qfrag, acc, lrow, hi, qs);
    kB = kn; vB0 = n0; vB1 = n1; }
  { KU kn; bf16x8 n0, n1; LK(6, kn); LV(6, n0, n1);
    attn_chunk(hpk[4], kA.v, vA0, vA1, wreg, qfrag, acc, lrow, hi, qs);
    kA = kn; vA0 = n0; vA1 = n1; }
  attn_chunk(hpk[5], kB.v, vB0, vB1, wreg, qfrag, acc, lrow, hi, qs);
  attn_chunk(hpk[6], kA.v, vA0, vA1, wreg, qfrag, acc, lrow, hi, qs);

#undef LK
#undef LV

  const float L = lrow + __shfl_xor(lrow, 32);
  const float invL = 1.f / L;
  const int qt = (w << 5) + q32;
  const int yq = bi * 8 + (qt >> 3);
  const int xq = bj * 8 + (q32 & 7);
  float* obase = out + ((size_t)(b * 256 + head * 32) * 4096) + yq * 64 + xq;
#pragma unroll
  for (int r = 0; r < 16; ++r) {
    const int d = (r & 3) + 8 * (r >> 2) + 4 * hi;
    obase[(size_t)d * 4096] = acc[r] * invL;
  }
}

extern "C" void kernel_launch(void* const* d_in, const int* in_sizes, int n_in,
                              void* d_out, int out_size, void* d_ws, size_t ws_size,
                              hipStream_t stream) {
  const float* x          = (const float*)d_in[0];
  const float* q_w        = (const float*)d_in[1];
  const float* kv_w       = (const float*)d_in[2];
  const float* height_rel = (const float*)d_in[3];
  const float* width_rel  = (const float*)d_in[4];
  float* out = (float*)d_out;

  unsigned short* q_bf = (unsigned short*)d_ws;            // 4,194,304 u16
  unsigned short* xT   = q_bf + (size_t)4194304;           // 8,388,608 u16
  unsigned short* w_bf = xT + (size_t)8388608;             //   131,072 u16
  unsigned short* kbuf = w_bf + (size_t)131072;            // 4,194,304 u16
  unsigned short* vpln = kbuf + (size_t)4194304;           // 10,321,920 u16

  haloattn_cvt<<<dim3(64, 4, 8), 256, 0, stream>>>(x, q_w, kv_w, xT, w_bf, vpln);
  haloattn_proj_mfma<<<dim3(32, 2, 8), 512, 0, stream>>>(xT, w_bf, q_bf, kbuf, vpln);
  haloattn_attn_direct<<<4096, 128, 0, stream>>>(q_bf, kbuf, vpln,
                                                 height_rel, width_rel, out);
}